// Round 2
// baseline (347.114 us; speedup 1.0000x reference)
//
#include <hip/hip_runtime.h>
#include <stdint.h>

#define NB 8
#define CC 256
#define TT 256
#define VV 25

typedef unsigned int u32;
typedef unsigned short u16;
typedef __attribute__((ext_vector_type(8))) short s16x8;
typedef __attribute__((ext_vector_type(4))) float f32x4;

__device__ __forceinline__ float bf2f(u16 u) { return __uint_as_float((u32)u << 16); }
__device__ __forceinline__ u16 f2bf(float f) {
    u32 u = __float_as_uint(f);
    u += 0x7fffu + ((u >> 16) & 1u);
    return (u16)(u >> 16);
}

__device__ __forceinline__ void gload_lds16(const void* g, void* l) {
    __builtin_amdgcn_global_load_lds(
        (const __attribute__((address_space(1))) u32*)g,
        (__attribute__((address_space(3))) u32*)l, 16, 0, 0);
}

// ---------------------------------------------------------------------------
// K1: x (N,C,T,V) f32 -> xT[b=(n*V+v)][t][c] bf16  (k-contiguous rows for MFMA A/B)
__global__ __launch_bounds__(256) void k_transpose_x(const float* __restrict__ x,
                                                     u16* __restrict__ xT) {
    __shared__ u16 L[25 * 32 * 34];
    const int tid = threadIdx.x;
    const int c0 = blockIdx.x * 32;
    const int t0 = blockIdx.y * 32;
    const int n  = blockIdx.z;
    for (int i = tid; i < 25600; i += 256) {
        int ci = i / 800;
        int rem = i - ci * 800;
        int t = rem / 25;
        int v = rem - t * 25;
        float f = x[(((size_t)(n * CC + c0 + ci)) * TT + t0) * VV + rem];
        L[(v * 32 + t) * 34 + ci] = f2bf(f);
    }
    __syncthreads();
    for (int i = tid; i < 12800; i += 256) {
        int row = i >> 4, cp = i & 15;
        int v = row >> 5, t = row & 31;
        u32 val = *(const u32*)&L[row * 34 + cp * 2];
        *(u32*)&xT[(((size_t)(n * VV + v)) * TT + t0 + t) * CC + c0 + cp * 2] = val;
    }
}

// ---------------------------------------------------------------------------
// K1b: key_rel (511,32) f32 -> krb[m][d] bf16, 512 rows (row 511 zeroed)
__global__ __launch_bounds__(256) void k_pack_krel(const float* __restrict__ kr,
                                                   u16* __restrict__ krb) {
    int g = blockIdx.x * 256 + threadIdx.x;
    if (g >= 16384) return;
    krb[g] = (g < 511 * 32) ? f2bf(kr[g]) : (u16)0;
}

// ---------------------------------------------------------------------------
// K1c: pack weights to bf16. q rows pre-scaled by 1/sqrt(32) * log2(e): the
// log2e fold makes softmax's exp a bare v_exp_f32 (exp2) downstream; softmax
// is exactly invariant to the uniform logit scale paired with exp2.
__global__ __launch_bounds__(256) void k_pack_w(const float* __restrict__ qkv_w,
                                                const float* __restrict__ attn_w,
                                                const float* __restrict__ qkv_b,
                                                u16* __restrict__ Wqk,
                                                u16* __restrict__ Wv,
                                                u16* __restrict__ Wo,
                                                float* __restrict__ bqk) {
    const float s = 0.17677669529663687f * 1.4426950408889634f;
    int g = blockIdx.x * 256 + threadIdx.x;
    if (g < 131072) {
        Wqk[g] = f2bf(qkv_w[g] * (g < 65536 ? s : 1.f));
    } else if (g < 196608) {
        Wv[g - 131072] = f2bf(qkv_w[g]);             // qkv_w rows 512..767
    } else if (g < 262144) {
        Wo[g - 196608] = f2bf(attn_w[g - 196608]);
    } else if (g < 262656) {
        int i = g - 262144;
        bqk[i] = qkv_b[i] * (i < 256 ? s : 1.f);
    }
}

// ---------------------------------------------------------------------------
// m97-style mainloop: 128x128 tile, BK=32, async global->LDS, 4 waves x (4x4) 16x16 tiles.
__device__ __forceinline__ void gemm_mainloop(const u16* __restrict__ Arow,
                                              const u16* __restrict__ Brow,
                                              u16* At, u16* Bt,
                                              int wave, int lane, f32x4 acc[4][4]) {
    const int srow = lane >> 2, scol = (lane & 3) * 8;
    const int quad = lane >> 4, l15 = lane & 15;
    for (int k0 = 0; k0 < 256; k0 += 32) {
#pragma unroll
        for (int it = 0; it < 2; ++it) {
            int ch = it * 4 + wave;
            gload_lds16(Arow + (size_t)(ch * 16 + srow) * 256 + k0 + scol, At + ch * 512 + lane * 8);
            gload_lds16(Brow + (size_t)(ch * 16 + srow) * 256 + k0 + scol, Bt + ch * 512 + lane * 8);
        }
        __syncthreads();
        s16x8 af[4], bfr[4];
#pragma unroll
        for (int i = 0; i < 4; ++i)
            af[i] = *(const s16x8*)&At[((wave & 1) * 64 + i * 16 + l15) * 32 + quad * 8];
#pragma unroll
        for (int j = 0; j < 4; ++j)
            bfr[j] = *(const s16x8*)&Bt[((wave >> 1) * 64 + j * 16 + l15) * 32 + quad * 8];
#pragma unroll
        for (int i = 0; i < 4; ++i)
#pragma unroll
            for (int j = 0; j < 4; ++j)
                acc[i][j] = __builtin_amdgcn_mfma_f32_16x16x32_bf16(af[i], bfr[j], acc[i][j], 0, 0, 0);
        __syncthreads();
    }
}

// ---------------------------------------------------------------------------
// K2a: C[t][o] = xT . Wqk^T + bqk  -> qT[b][h][t][32], kT[b][h][s][32]
__global__ __launch_bounds__(256) void k_gemm_qk(const u16* __restrict__ xT,
                                                 const u16* __restrict__ Wqk,
                                                 const float* __restrict__ bqk,
                                                 u16* __restrict__ qT,
                                                 u16* __restrict__ kT) {
    __shared__ __align__(16) u16 At[128 * 32];
    __shared__ __align__(16) u16 Bt[128 * 32];
    const int tid = threadIdx.x, wave = tid >> 6, lane = tid & 63;
    const int quad = lane >> 4, l15 = lane & 15;
    const int n0 = blockIdx.x * 128;     // o
    const int m0 = blockIdx.y * 128;     // t
    const int b  = blockIdx.z;
    const u16* Arow = xT + (size_t)b * 65536 + (size_t)m0 * 256;
    const u16* Brow = Wqk + (size_t)n0 * 256;
    f32x4 acc[4][4];
#pragma unroll
    for (int i = 0; i < 4; ++i)
#pragma unroll
        for (int j = 0; j < 4; ++j) acc[i][j] = (f32x4){0.f, 0.f, 0.f, 0.f};
    gemm_mainloop(Arow, Brow, At, Bt, wave, lane, acc);

    const bool isq = (n0 < 256);
    u16* base = isq ? qT : kT;
    const int on0 = (isq ? n0 : n0 - 256) + (wave >> 1) * 64;
#pragma unroll
    for (int j = 0; j < 4; ++j) {
        int o = on0 + j * 16 + l15;
        float bias = bqk[(isq ? 0 : 256) + o];
        u16* dcol = base + (size_t)(b * 8 + (o >> 5)) * 8192 + (o & 31);
#pragma unroll
        for (int i = 0; i < 4; ++i) {
            int tbase = m0 + (wave & 1) * 64 + i * 16 + quad * 4;
#pragma unroll
            for (int r = 0; r < 4; ++r)
                dcol[(size_t)(tbase + r) * 32] = f2bf(acc[i][j][r] + bias);
        }
    }
}

// ---------------------------------------------------------------------------
// K2b (used twice): C[o][t] = W . Bsrc^T + bias -> Out[b][o][t]
__global__ __launch_bounds__(256) void k_gemm_av(const u16* __restrict__ Wb,
                                                 const float* __restrict__ bias,
                                                 const u16* __restrict__ Bsrc,
                                                 u16* __restrict__ Out) {
    __shared__ __align__(16) u16 At[128 * 32];
    __shared__ __align__(16) u16 Bt[128 * 32];
    const int tid = threadIdx.x, wave = tid >> 6, lane = tid & 63;
    const int quad = lane >> 4, l15 = lane & 15;
    const int n0 = blockIdx.x * 128;     // t
    const int m0 = blockIdx.y * 128;     // o
    const int b  = blockIdx.z;
    const u16* Arow = Wb + (size_t)m0 * 256;
    const u16* Brow = Bsrc + (size_t)b * 65536 + (size_t)n0 * 256;
    f32x4 acc[4][4];
#pragma unroll
    for (int i = 0; i < 4; ++i)
#pragma unroll
        for (int j = 0; j < 4; ++j) acc[i][j] = (f32x4){0.f, 0.f, 0.f, 0.f};
    gemm_mainloop(Arow, Brow, At, Bt, wave, lane, acc);

    u16* ob = Out + (size_t)b * 65536;
    const int nb = n0 + (wave >> 1) * 64 + l15;
#pragma unroll
    for (int i = 0; i < 4; ++i) {
        int o_i = m0 + (wave & 1) * 64 + i * 16 + quad * 4;
#pragma unroll
        for (int r = 0; r < 4; ++r) {
            float bv = bias[o_i + r];
            u16* orow = ob + (size_t)(o_i + r) * 256 + nb;
#pragma unroll
            for (int j = 0; j < 4; ++j)
                orow[j * 16] = f2bf(acc[i][j][r] + bv);
        }
    }
}

// ---------------------------------------------------------------------------
// K3: wave-autonomous MFMA attention, v3 (de-risked from v2).
//   S = Q·K^T (K direct from global, L2-hot via XCD grouping)
//   rel: R tiles streamed IN REGISTERS (rolling 2-tile window); diagonal
//        gather via source-side cndmask + one __shfl per (n,r)
//        (src lane quad*16+((l15+K)&15), K=15-tl-r, is n-invariant;
//        tile-select at the SOURCE lane is l15 < K). Hand-verified vs the
//        original band indexing incl. the tile-carry boundary.
//   softmax: per-lane partial trees + __shfl_xor 1/2/4/8 (proven pattern);
//        exp2f (log2e pre-folded into q scale); 1/sum deferred to O epilogue.
//   P: original proven path — row-major stride-280 band, scalar u16 writes
//        (unnormalized), ds_read_b128 A-fragments. (v2's s-major+tr_read and
//        DPP reduce were the failure suspects; removed this round.)
// Zero __syncthreads; band is wave-private (same-wave LDS ordering).
// LDS 4 x 8.96KB. Grid: 6400 1-D blocks remapped so the 4 t-tiles of one bh
// are CONSECUTIVE on ONE XCD (K/V L2-hot across them).
__global__ __launch_bounds__(256, 4) void k_attention_mfma(const u16* __restrict__ qT,
                                                           const u16* __restrict__ kT,
                                                           const u16* __restrict__ vb,
                                                           const u16* __restrict__ krb,
                                                           u16* __restrict__ attn) {
    __shared__ __align__(16) u16 RP[4][16 * 280];

    const int tid = threadIdx.x;
    const int bx = blockIdx.x;
    // bijective XCD grouping: xcd = bx & 7 (HW round-robin), 4 consecutive
    // dispatches per bh on that XCD
    const int xcd = bx & 7;
    const int ii  = bx >> 3;
    const int bh  = xcd * 200 + (ii >> 2);
    const int tt  = ii & 3;
    const int b = bh >> 3, h = bh & 7;
    const int wave = tid >> 6, lane = tid & 63;
    const int quad = lane >> 4, l15 = lane & 15;
    const int t0w = tt * 64 + wave * 16;    // this wave's first t-row
    const int tl = quad * 4;                // C-layout row base (t-local)

    u16* rp = &RP[wave][0];
    const u16* qg  = qT  + (size_t)bh * 8192;
    const u16* kg  = kT  + (size_t)bh * 8192;
    const u16* vg  = vb  + (size_t)bh * 8192;
    const u16* krg = krb + (size_t)(240 - t0w) * 32;  // m = col + 240 - t0w

    // A fragment: Q rows t0w..t0w+15, k-contiguous
    s16x8 afrag = *(const s16x8*)(qg + (size_t)(t0w + l15) * 32 + quad * 8);
    const f32x4 z4 = {0.f, 0.f, 0.f, 0.f};

    // ---- S = Q K^T (16 tiles over s)
    f32x4 acc[16];
    __builtin_amdgcn_s_setprio(1);
#pragma unroll
    for (int n = 0; n < 16; ++n) {
        s16x8 kf = *(const s16x8*)(kg + (size_t)(n * 16 + l15) * 32 + quad * 8);
        acc[n] = __builtin_amdgcn_mfma_f32_16x16x32_bf16(afrag, kf, z4, 0, 0, 0);
    }
    __builtin_amdgcn_s_setprio(0);

    // ---- rel: R tiles streamed in registers; gather S[t][s] += R[t][s-t+15]
    int srcl[4];
    bool msrc[4];
#pragma unroll
    for (int r = 0; r < 4; ++r) {
        int K = 15 - tl - r;                    // per-(quad,r) shift amount
        srcl[r] = quad * 16 + ((l15 + K) & 15); // dest-role: pull lane
        msrc[r] = l15 < K;                      // source-role: feeds a carry dest
    }
    f32x4 rc = __builtin_amdgcn_mfma_f32_16x16x32_bf16(
        afrag, *(const s16x8*)(krg + (size_t)l15 * 32 + quad * 8), z4, 0, 0, 0);
#pragma unroll
    for (int n = 0; n < 16; ++n) {
        f32x4 rn = __builtin_amdgcn_mfma_f32_16x16x32_bf16(
            afrag, *(const s16x8*)(krg + (size_t)((n + 1) * 16 + l15) * 32 + quad * 8),
            z4, 0, 0, 0);
#pragma unroll
        for (int r = 0; r < 4; ++r) {
            float vsel = msrc[r] ? rn[r] : rc[r];
            acc[n][r] += __shfl(vsel, srcl[r], 64);
        }
        rc = rn;
    }

    // ---- wave-local softmax (logits pre-scaled by log2e; exp2 native)
    float invr[4];
#pragma unroll
    for (int r = 0; r < 4; ++r) {
        float mr[8];
#pragma unroll
        for (int n = 0; n < 8; ++n) mr[n] = fmaxf(acc[n][r], acc[n + 8][r]);
#pragma unroll
        for (int n = 0; n < 4; ++n) mr[n] = fmaxf(mr[n], mr[n + 4]);
        float m = fmaxf(fmaxf(mr[0], mr[1]), fmaxf(mr[2], mr[3]));
#pragma unroll
        for (int off = 1; off < 16; off <<= 1) m = fmaxf(m, __shfl_xor(m, off, 64));
#pragma unroll
        for (int n = 0; n < 16; ++n) acc[n][r] = exp2f(acc[n][r] - m);
        float sr[8];
#pragma unroll
        for (int n = 0; n < 8; ++n) sr[n] = acc[n][r] + acc[n + 8][r];
#pragma unroll
        for (int n = 0; n < 4; ++n) sr[n] = sr[n] + sr[n + 4];
        float s = (sr[0] + sr[1]) + (sr[2] + sr[3]);
#pragma unroll
        for (int off = 1; off < 16; off <<= 1) s += __shfl_xor(s, off, 64);
        invr[r] = 1.f / s;   // applied in the O epilogue, not on P
    }

    // ---- P (unnormalized) over the band — wave-local ordering, no barrier
#pragma unroll
    for (int n = 0; n < 16; ++n) {
#pragma unroll
        for (int r = 0; r < 4; ++r)
            rp[(tl + r) * 280 + n * 16 + l15] = f2bf(acc[n][r]);
    }

    // ---- O = P V^T (V direct from global; 2 d-tiles x 8 k-steps)
#pragma unroll
    for (int j = 0; j < 2; ++j) {
        f32x4 o = {0.f, 0.f, 0.f, 0.f};
        __builtin_amdgcn_s_setprio(1);
#pragma unroll
        for (int ks = 0; ks < 8; ++ks) {
            s16x8 a  = *(const s16x8*)&rp[l15 * 280 + ks * 32 + quad * 8];
            s16x8 bv = *(const s16x8*)(vg + (size_t)(j * 16 + l15) * 256 + ks * 32 + quad * 8);
            o = __builtin_amdgcn_mfma_f32_16x16x32_bf16(a, bv, o, 0, 0, 0);
        }
        __builtin_amdgcn_s_setprio(0);
        u16* ob = attn + ((size_t)b * 256 + t0w + tl) * 256 + h * 32 + j * 16 + l15;
        ob[0]   = f2bf(o[0] * invr[0]);
        ob[256] = f2bf(o[1] * invr[1]);
        ob[512] = f2bf(o[2] * invr[2]);
        ob[768] = f2bf(o[3] * invr[3]);
    }
}

// ---------------------------------------------------------------------------
// K5: out[n][o][t][v] = relu((y[b=(n,v)][o][t] + x[n][o][t][v]) * inv[o] + shift[o])
__global__ __launch_bounds__(256) void k_final(const u16* __restrict__ y,
                                               const float* __restrict__ x,
                                               const float* __restrict__ gamma,
                                               const float* __restrict__ beta,
                                               const float* __restrict__ mean,
                                               const float* __restrict__ var,
                                               float* __restrict__ out) {
    __shared__ float tile[1600];
    const int tid = threadIdx.x;
    const int t0 = blockIdx.x * 64;
    const int o  = blockIdx.y;
    const int n  = blockIdx.z;
    float inv = gamma[o] * rsqrtf(var[o] + 1e-5f);
    float sh  = beta[o] - mean[o] * inv;
    for (int p = tid; p < 1600; p += 256) {
        int v = p >> 6, j = p & 63;
        tile[j * VV + v] = bf2f(y[(((size_t)(n * VV + v)) * CC + o) * TT + t0 + j]);
    }
    __syncthreads();
    size_t gbase = (((size_t)(n * CC + o)) * TT + t0) * VV;
    for (int i = tid; i < 1600; i += 256) {
        float val = tile[i] + x[gbase + i];
        val = val * inv + sh;
        out[gbase + i] = fmaxf(val, 0.f);
    }
}

// ---------------------------------------------------------------------------
extern "C" void kernel_launch(void* const* d_in, const int* in_sizes, int n_in,
                              void* d_out, int out_size, void* d_ws, size_t ws_size,
                              hipStream_t stream) {
    const float* x        = (const float*)d_in[0];
    const float* qkv_w    = (const float*)d_in[1];
    const float* qkv_b    = (const float*)d_in[2];
    const float* key_rel  = (const float*)d_in[3];
    const float* attn_w   = (const float*)d_in[4];
    const float* attn_b   = (const float*)d_in[5];
    const float* bn_gamma = (const float*)d_in[6];
    const float* bn_beta  = (const float*)d_in[7];
    const float* bn_mean  = (const float*)d_in[8];
    const float* bn_var   = (const float*)d_in[9];
    float* out = (float*)d_out;

    // d_ws: 5 x 26,214,400 = 131,072,000 bytes
    char* ws = (char*)d_ws;
    u16* xT    = (u16*)ws;
    u16* qT    = (u16*)(ws + 26214400);
    u16* kT    = (u16*)(ws + 52428800);
    u16* vb    = (u16*)(ws + 78643200);
    u16* attnT = (u16*)(ws + 104857600);
    u16* y     = qT;    // qT dead after attention; reuse for y

    // d_out doubles as scratch for packed weights (dead before k_final overwrites)
    char* outc = (char*)d_out;
    u16* Wqk   = (u16*)outc;                // 262,144 B
    u16* Wv    = (u16*)(outc + 262144);     // 131,072 B
    u16* Wo    = (u16*)(outc + 393216);     // 131,072 B
    float* bqk = (float*)(outc + 524288);   //   2,048 B
    u16* krb   = (u16*)(outc + 526336);     //  32,768 B

    k_pack_w<<<1026, 256, 0, stream>>>(qkv_w, attn_w, qkv_b, Wqk, Wv, Wo, bqk);
    k_pack_krel<<<64, 256, 0, stream>>>(key_rel, krb);
    k_transpose_x<<<dim3(8, 8, 8), 256, 0, stream>>>(x, xT);
    k_gemm_qk<<<dim3(4, 2, 200), 256, 0, stream>>>(xT, Wqk, bqk, qT, kT);
    k_gemm_av<<<dim3(2, 2, 200), 256, 0, stream>>>(Wv, qkv_b + 512, xT, vb);
    k_attention_mfma<<<dim3(6400), 256, 0, stream>>>(qT, kT, vb, krb, attnT);
    k_gemm_av<<<dim3(2, 2, 200), 256, 0, stream>>>(Wo, attn_b, attnT, y);
    k_final<<<dim3(4, 256, 8), 256, 0, stream>>>(y, x, bn_gamma, bn_beta, bn_mean, bn_var, out);
}